// Round 12
// baseline (239.109 us; speedup 1.0000x reference)
//
#include <hip/hip_runtime.h>

typedef __attribute__((ext_vector_type(8))) __bf16 bf16x8;
typedef __attribute__((ext_vector_type(4))) float  f32x4;

#define DEV __device__ __forceinline__

DEV void async_copy16(const void* g, void* l) {
  __builtin_amdgcn_global_load_lds((const __attribute__((address_space(1))) void*)g,
                                   (__attribute__((address_space(3))) void*)l, 16, 0, 0);
}

// load element i of a raw input as float; isbf chooses bf16 vs fp32 interpretation
DEV float ldf(const void* p, size_t i, int isbf) {
  if (isbf) {
    unsigned int w = ((unsigned int)((const unsigned short*)p)[i]) << 16;
    float f; __builtin_memcpy(&f, &w, 4); return f;
  }
  return ((const float*)p)[i];
}

// uniform per-block dtype probe on x's first 64 halfwords (scalar loads; all lanes agree)
DEV int detect_isbf(const unsigned short* __restrict__ x) {
  int bad = 0;
#pragma unroll
  for (int i = 0; i < 64; i++) {
    int e = (x[i] >> 7) & 0xFF;
    bad |= (e >= 0x90) ? 1 : 0;
  }
  return !bad;
}

// ---- fused prep: z<4 -> transpose weight z into bf16 [C][R]; z==4 -> x cast (fp32 only) + bias ----
__global__ __launch_bounds__(256) void prep(const void* __restrict__ Wq,
                                            const void* __restrict__ Wk,
                                            const void* __restrict__ Wv,
                                            const void* __restrict__ Wo,
                                            const void* __restrict__ x,
                                            const void* __restrict__ bq,
                                            const void* __restrict__ bk,
                                            const void* __restrict__ bv,
                                            const void* __restrict__ bo,
                                            __bf16* __restrict__ Wt,
                                            __bf16* __restrict__ Wot,
                                            __bf16* __restrict__ x_bf,
                                            float* __restrict__ bias) {
  __shared__ float tile[32][33];
  const int isbf = detect_isbf((const unsigned short*)x);
  const int tid = threadIdx.x;
  const int z = blockIdx.z;

  if (z < 4) {
    const void* in = (z == 0) ? Wq : (z == 1) ? Wk : (z == 2) ? Wv : Wo;
    __bf16* out = (z < 3) ? (Wt + (size_t)z * 1024 * 1024) : Wot;
    const int tx = tid & 31, ty = tid >> 5;
    const int r0 = blockIdx.y * 32, c0 = blockIdx.x * 32;
#pragma unroll
    for (int i = 0; i < 4; i++) {
      int r = ty + i * 8;
      tile[r][tx] = ldf(in, (size_t)(r0 + r) * 1024 + c0 + tx, isbf);
    }
    __syncthreads();
#pragma unroll
    for (int i = 0; i < 4; i++) {
      int r = ty + i * 8;
      out[(size_t)(c0 + r) * 1024 + r0 + tx] = (__bf16)tile[tx][r];
    }
  } else {
    const int id = blockIdx.y * 32 + blockIdx.x;  // 0..1023
    if (!isbf) {
#pragma unroll
      for (int j = 0; j < 4; j++) {
        int idx = id * 1024 + j * 256 + tid;
        float4 f = ((const float4*)x)[idx];
        union { __bf16 h[4]; uint2 u; } pk;
        pk.h[0] = (__bf16)f.x; pk.h[1] = (__bf16)f.y;
        pk.h[2] = (__bf16)f.z; pk.h[3] = (__bf16)f.w;
        ((uint2*)x_bf)[idx] = pk.u;
      }
    }
    if (id < 16) {
      int i = id * 256 + tid;
      if (i < 1024)      bias[i] = ldf(bq, i, isbf);
      else if (i < 2048) bias[i] = ldf(bk, i - 1024, isbf);
      else if (i < 3072) bias[i] = ldf(bv, i - 2048, isbf);
      else               bias[i] = ldf(bo, i - 3072, isbf);
    }
  }
}

// ---------------- GEMM: C[M,NT-tiled] = A[M,K] @ Bt[N,K]^T + bias ----------------
// ALT=1: read A from Aalt (raw input x) when input is bf16.
// NPX: n-panels per XCD. 1-D grid; decode pins a contiguous set of n-panels to one
// XCD (id%8 round-robin, validated by attn round 11: FETCH 69.7->12.3 MB) and walks
// m fastest within it, so the Bt slice (NT*K*2B*NPX <= 768 KB) stays L2-resident.
template <int DYN, int NT, int ALT, int NPX>
__global__ __launch_bounds__(256, 3) void gemm_bt(const __bf16* __restrict__ A,
                                                  const __bf16* __restrict__ Aalt,
                                                  const __bf16* __restrict__ Bt,
                                                  const float* __restrict__ bias,
                                                  void* __restrict__ Cout,
                                                  const unsigned short* __restrict__ xdet,
                                                  int M, int N, int K) {
  constexpr int WN = NT / 2;
  constexpr int JB = WN / 16;
  constexpr int NR = NT / 32;
  __shared__ __align__(16) __bf16 As[128 * 64];
  __shared__ __align__(16) __bf16 Bs[NT * 64];
  const int tid = threadIdx.x;
  const int wid = tid >> 6, lane = tid & 63;
  const int xcd = blockIdx.x & 7, t = blockIdx.x >> 3;
  const int m_blk = (t & 31) * 128;
  const int n_blk = (xcd * NPX + (t >> 5)) * NT;
  const int wm = (wid & 1) * 64, wn = (wid >> 1) * WN;
  const int l8 = lane >> 3, l7 = lane & 7;
  const int cc = l7 ^ (l8 & 7);
  const int q4 = lane >> 4, l15 = lane & 15;

  int isbf = 1;
  if (DYN || ALT) isbf = detect_isbf(xdet);
  const __bf16* Ap = (ALT && isbf) ? Aalt : A;

  f32x4 acc[4][JB] = {};

  for (int kb = 0; kb < K; kb += 64) {
    __syncthreads();
#pragma unroll
    for (int i = 0; i < 4; i++) {
      int row = i * 32 + wid * 8 + l8;
      async_copy16(Ap + (size_t)(m_blk + row) * K + kb + cc * 8,
                   As + (i * 32 + wid * 8) * 64);
    }
#pragma unroll
    for (int i = 0; i < NR; i++) {
      int row = i * 32 + wid * 8 + l8;
      async_copy16(Bt + (size_t)(n_blk + row) * K + kb + cc * 8,
                   Bs + (i * 32 + wid * 8) * 64);
    }
    __syncthreads();
#pragma unroll
    for (int k0 = 0; k0 < 64; k0 += 32) {
      bf16x8 a[4], b[JB];
#pragma unroll
      for (int i = 0; i < 4; i++) {
        int ra = wm + i * 16 + l15;
        int ba = ra * 8 + (((k0 >> 3) + q4) ^ (ra & 7));
        a[i] = *(const bf16x8*)&As[ba * 8];
      }
#pragma unroll
      for (int j = 0; j < JB; j++) {
        int rb = wn + j * 16 + l15;
        int bb = rb * 8 + (((k0 >> 3) + q4) ^ (rb & 7));
        b[j] = *(const bf16x8*)&Bs[bb * 8];
      }
#pragma unroll
      for (int i = 0; i < 4; i++)
#pragma unroll
        for (int j = 0; j < JB; j++)
          acc[i][j] = __builtin_amdgcn_mfma_f32_16x16x32_bf16(a[i], b[j], acc[i][j], 0, 0, 0);
    }
  }

  float bcol[JB];
#pragma unroll
  for (int j = 0; j < JB; j++) bcol[j] = bias[n_blk + wn + j * 16 + l15];
#pragma unroll
  for (int i = 0; i < 4; i++)
#pragma unroll
    for (int j = 0; j < JB; j++) {
      int col = n_blk + wn + j * 16 + l15;
#pragma unroll
      for (int r = 0; r < 4; r++) {
        int row = m_blk + wm + i * 16 + q4 * 4 + r;
        float v = acc[i][j][r] + bcol[j];
        size_t idx = (size_t)row * N + col;
        if (DYN && !isbf) ((float*)Cout)[idx] = v;
        else              ((__bf16*)Cout)[idx] = (__bf16)v;
      }
    }
}

// ---------------- LN + RoPE + V-transpose (fused) ----------------
__global__ __launch_bounds__(256) void ln_rope_v(const __bf16* __restrict__ qkv,
                                                 const void* __restrict__ rcos,
                                                 const void* __restrict__ rsin,
                                                 const void* __restrict__ qw,
                                                 const void* __restrict__ qb,
                                                 const void* __restrict__ kw,
                                                 const void* __restrict__ kb_,
                                                 const unsigned short* __restrict__ xdet,
                                                 __bf16* __restrict__ Qp,
                                                 __bf16* __restrict__ Kp,
                                                 __bf16* __restrict__ Vt) {
  __shared__ __bf16 vt[64][68];
  const int isbf = detect_isbf(xdet);
  const int tid = threadIdx.x, w = tid >> 6, lane = tid & 63;
  const int bh = blockIdx.y, h = bh & 15, b = bh >> 4;
  const int n0 = blockIdx.x * 64;

  float gq = ldf(qw, lane, isbf), bq_ = ldf(qb, lane, isbf);
  float gk = ldf(kw, lane, isbf), bk_ = ldf(kb_, lane, isbf);

#pragma unroll 2
  for (int t = 0; t < 16; t++) {
    const int n = n0 + w * 16 + t;
    const size_t tok = (size_t)b * 2048 + n;
    const __bf16* base = qkv + tok * 3072 + h * 192;
    float qv = (float)base[lane], kv = (float)base[64 + lane], vv = (float)base[128 + lane];

    float sq = qv, sk = kv;
#pragma unroll
    for (int m = 1; m < 64; m <<= 1) { sq += __shfl_xor(sq, m, 64); sk += __shfl_xor(sk, m, 64); }
    float muq = sq * (1.0f / 64.0f), muk = sk * (1.0f / 64.0f);
    float tq = qv - muq, tk = kv - muk;
    float vq = tq * tq, vk = tk * tk;
#pragma unroll
    for (int m = 1; m < 64; m <<= 1) { vq += __shfl_xor(vq, m, 64); vk += __shfl_xor(vk, m, 64); }
    float rsq = rsqrtf(vq * (1.0f / 64.0f) + 1e-6f);
    float rsk = rsqrtf(vk * (1.0f / 64.0f) + 1e-6f);
    float qn = tq * rsq * gq + bq_;
    float kn = tk * rsk * gk + bk_;

    float c = ldf(rcos, tok * 64 + lane, isbf), s = ldf(rsin, tok * 64 + lane, isbf);
    float qpart = __shfl_xor(qn, 32, 64), kpart = __shfl_xor(kn, 32, 64);
    float qrh = (lane < 32) ? -qpart : qpart;
    float krh = (lane < 32) ? -kpart : kpart;

    const size_t oidx = ((size_t)bh * 2048 + n) * 64 + lane;
    Qp[oidx] = (__bf16)((qn * c + qrh * s) * 0.1803368801111204f);  // 0.125 * log2(e)
    Kp[oidx] = (__bf16)(kn * c + krh * s);
    vt[lane][w * 16 + t] = (__bf16)vv;
  }
  __syncthreads();
  const int row = tid >> 2, qt = tid & 3;
  size_t gbase = (size_t)bh * 64 * 2048 + (size_t)row * 2048 + n0 + qt * 16;
#pragma unroll
  for (int u = 0; u < 4; u++)
    *(uint2*)&Vt[gbase + u * 4] = *(const uint2*)&vt[row][qt * 16 + u * 4];
}

// ---------------- flash attention: 64 q/wave, K-split x2, KT=32, XCD-swizzled ----------------
// Wave tile 64q x 32k: ak/av fragment reads amortize over 2x the MFMA work -> DS-pipe
// cycles per unit work drop ~33% (round 11 showed DS ~66% busy = the real bottleneck).
// Block = 256 q; grid 512 = 2 blocks/CU (VGPR ~150, LB(256,2)), exact residency.
// XCD decode pins 8 (bh,split) groups per XCD (2 MB K/V -> L2-resident).
__global__ __launch_bounds__(256, 2) void attn(const __bf16* __restrict__ Qp,
                                               const __bf16* __restrict__ Kp,
                                               const __bf16* __restrict__ Vt,
                                               float* __restrict__ O0,
                                               float* __restrict__ O1,
                                               float* __restrict__ lpart) {
  __shared__ __align__(16) __bf16 sK[2][2048];   // [buf][(ks*2+c)*64+lane]*8
  __shared__ __align__(16) __bf16 sV[2][2048];   // [buf][(ds*64+lane)]*8
  __shared__ __align__(16) __bf16 sP[4][2048];   // per-wave, B-frag order (64q x 32k)

  const int tid = threadIdx.x, wid = tid >> 6, lane = tid & 63;
  const int q4 = lane >> 4, l15 = lane & 15;
  // XCD-locality decode: 512 blocks; 8 groups x 8 qblk per XCD
  const int xcd = blockIdx.x & 7, t = blockIdx.x >> 3;
  const int qblk = t & 7;
  const int g = xcd * 8 + (t >> 3);      // 0..63
  const int bh = g & 31, split = g >> 5;
  const int q0w = qblk * 256 + wid * 64;
  const int kt0 = split * 1024;
  const __bf16* Qb = Qp + (size_t)bh * 2048 * 64;
  const __bf16* Kb = Kp + (size_t)bh * 2048 * 64;
  const __bf16* Vb = Vt + (size_t)bh * 64 * 2048;
  float* Op = split ? O1 : O0;
  __bf16* sPw = &sP[wid][0];
  const int pbase = (q4 >> 1) * 128 + l15 * 8 + (q4 & 1) * 4;

  // Q fragments (B-operand): B[q=l15][k=q4*8+j], 4 q-subs x 2 d-chains
  bf16x8 qf[4][2];
#pragma unroll
  for (int qs = 0; qs < 4; qs++)
#pragma unroll
    for (int c = 0; c < 2; c++)
      qf[qs][c] = *(const bf16x8*)&Qb[(size_t)(q0w + qs * 16 + l15) * 64 + c * 32 + q4 * 8];

  // all-ones A-fragment -> l row sums on the matrix pipe
  bf16x8 ones8;
#pragma unroll
  for (int i = 0; i < 8; i++) ones8[i] = (__bf16)1.0f;

  f32x4 o[4][4] = {};
  f32x4 l_acc[4] = {};

#define STAGE(kt, bf)                                                                    \
  do {                                                                                   \
    async_copy16(Kb + (size_t)((kt) + (wid >> 1) * 16 + l15) * 64 + (wid & 1) * 32 + q4 * 8, \
                 &sK[bf][wid * 512]);                                                    \
    async_copy16(Vb + (size_t)(wid * 16 + l15) * 2048 + (kt) + q4 * 8,                   \
                 &sV[bf][wid * 512]);                                                    \
  } while (0)

  STAGE(kt0, 0);

  for (int it = 0; it < 32; ++it) {
    const int buf = it & 1;
    __syncthreads();  // readers of buf^1 done + loads into buf landed
    if (it < 31) STAGE(kt0 + (it + 1) * 32, buf ^ 1);

    // ---- QK^T (S^T): A = K rows (2 ks-subs), B = Q (4 q-subs), 2 d-chains ----
    bf16x8 ak[2][2];
#pragma unroll
    for (int ks = 0; ks < 2; ks++)
#pragma unroll
      for (int c = 0; c < 2; c++)
        ak[ks][c] = *(const bf16x8*)&sK[buf][((ks * 2 + c) * 64 + lane) * 8];

#pragma unroll
    for (int qs = 0; qs < 4; qs++) {
#pragma unroll
      for (int ks = 0; ks < 2; ks++) {
        f32x4 z = {0.f, 0.f, 0.f, 0.f};
        z = __builtin_amdgcn_mfma_f32_16x16x32_bf16(ak[ks][0], qf[qs][0], z, 0, 0, 0);
        z = __builtin_amdgcn_mfma_f32_16x16x32_bf16(ak[ks][1], qf[qs][1], z, 0, 0, 0);
        // no-max softmax: p = exp2(s); truncate-pack to bf16 via v_perm
        uint2 pk;
        {
          float p0 = __builtin_amdgcn_exp2f(z[0]);
          float p1 = __builtin_amdgcn_exp2f(z[1]);
          pk.x = __builtin_amdgcn_perm(__builtin_bit_cast(unsigned int, p1),
                                       __builtin_bit_cast(unsigned int, p0), 0x07060302u);
          float p2 = __builtin_amdgcn_exp2f(z[2]);
          float p3 = __builtin_amdgcn_exp2f(z[3]);
          pk.y = __builtin_amdgcn_perm(__builtin_bit_cast(unsigned int, p3),
                                       __builtin_bit_cast(unsigned int, p2), 0x07060302u);
        }
        *(uint2*)&sPw[qs * 512 + ks * 256 + pbase] = pk;
      }
    }
    asm volatile("s_waitcnt lgkmcnt(0)" ::: "memory");  // P writes -> reads (same wave)

    // ---- PV (O^T += V^T.P) + l += ones.P on the matrix pipe ----
    bf16x8 pb[4];
#pragma unroll
    for (int qs = 0; qs < 4; qs++)
      pb[qs] = *(const bf16x8*)&sPw[(qs * 64 + lane) * 8];
#pragma unroll
    for (int qs = 0; qs < 4; qs++)
      l_acc[qs] = __builtin_amdgcn_mfma_f32_16x16x32_bf16(ones8, pb[qs], l_acc[qs], 0, 0, 0);
#pragma unroll
    for (int ds = 0; ds < 4; ds++) {
      bf16x8 av = *(const bf16x8*)&sV[buf][(ds * 64 + lane) * 8];
#pragma unroll
      for (int qs = 0; qs < 4; qs++)
        o[qs][ds] = __builtin_amdgcn_mfma_f32_16x16x32_bf16(av, pb[qs], o[qs][ds], 0, 0, 0);
    }
  }
#undef STAGE

  // ---- epilogue: fp32 partial O ([bh][q][d]) and fp32 partial l ----
#pragma unroll
  for (int qs = 0; qs < 4; qs++) {
    const int q = q0w + qs * 16 + l15;
    if (q4 == 0) lpart[(size_t)(split * 32 + bh) * 2048 + q] = l_acc[qs][0];
    size_t base = ((size_t)bh * 2048 + q) * 64;
#pragma unroll
    for (int ds = 0; ds < 4; ds++)
      *(f32x4*)&Op[base + ds * 16 + q4 * 4] = o[qs][ds];
  }
}

// ---------------- combine: Obuf = (O0+O1) / (l0+l1), bf16 [b][q][h*64+d] ----------------
__global__ __launch_bounds__(256) void combine(const float* __restrict__ O0,
                                               const float* __restrict__ O1,
                                               const float* __restrict__ lpart,
                                               __bf16* __restrict__ Obuf) {
  const int idx = blockIdx.x * 256 + threadIdx.x;  // 1,048,576 threads x 4 d
  const int d4 = idx & 15, q = (idx >> 4) & 2047, bh = idx >> 15;
  const int b = bh >> 4, h = bh & 15;
  const size_t po = ((size_t)bh * 2048 + q) * 64 + d4 * 4;
  f32x4 a = *(const f32x4*)&O0[po];
  f32x4 c = *(const f32x4*)&O1[po];
  float l = lpart[(size_t)bh * 2048 + q] + lpart[(size_t)(32 + bh) * 2048 + q];
  float rl = 1.0f / l;
  union { __bf16 h4[4]; uint2 u; } pk;
#pragma unroll
  for (int r = 0; r < 4; r++) pk.h4[r] = (__bf16)((a[r] + c[r]) * rl);
  *(uint2*)&Obuf[((size_t)(b * 2048 + q)) * 1024 + h * 64 + d4 * 4] = pk.u;
}

extern "C" void kernel_launch(void* const* d_in, const int* in_sizes, int n_in,
                              void* d_out, int out_size, void* d_ws, size_t ws_size,
                              hipStream_t stream) {
  const void* x   = d_in[0];
  const void* rc  = d_in[1];
  const void* rs  = d_in[2];
  const void* Wq  = d_in[3];
  const void* bq  = d_in[4];
  const void* Wk  = d_in[5];
  const void* bk  = d_in[6];
  const void* Wv  = d_in[7];
  const void* bv  = d_in[8];
  const void* qnw = d_in[9];
  const void* qnb = d_in[10];
  const void* knw = d_in[11];
  const void* knb = d_in[12];
  const void* Wo  = d_in[13];
  const void* bo  = d_in[14];
  const unsigned short* xdet = (const unsigned short*)x;

  // temporal aliasing plan:
  //  [0, 25165824)        qkv bf16 (gemm0 -> ln_rope_v), then O0/O1 fp32 (attn -> combine)
  //  [25165824, 33554432) x_bf (prep -> gemm0, fp32 path only; dead before attn)
  //  [33554432, 41943040) Qp (ln_rope_v -> attn), then Obuf (combine -> gemm1)
  char* ws = (char*)d_ws;
  __bf16* qkv   = (__bf16*)ws;
  float*  O0    = (float*)ws;                 // 16 MB
  float*  O1    = (float*)(ws + 16777216);    // 16 MB
  __bf16* x_bf  = (__bf16*)(ws + 25165824);
  __bf16* Qp    = (__bf16*)(ws + 33554432);
  __bf16* Obuf  = (__bf16*)(ws + 33554432);
  __bf16* Kp    = (__bf16*)(ws + 41943040);
  __bf16* Vt    = (__bf16*)(ws + 50331648);
  __bf16* Wt    = (__bf16*)(ws + 58720256);   // [3072][1024] 6 MB
  __bf16* Wot   = (__bf16*)(ws + 65011712);   // [1024][1024] 2 MB
  float*  bias  = (float*)(ws + 67108864);    // [4096]
  float*  lprt  = (float*)(ws + 67125248);    // [2][32][2048] fp32, 512 KB

  prep<<<dim3(32, 32, 5), 256, 0, stream>>>(Wq, Wk, Wv, Wo, x, bq, bk, bv, bo,
                                            Wt, Wot, x_bf, bias);
  gemm_bt<0, 128, 1, 3><<<768, 256, 0, stream>>>(x_bf, (const __bf16*)x, Wt, bias,
                                                 qkv, xdet, 4096, 3072, 1024);
  ln_rope_v<<<dim3(32, 32), 256, 0, stream>>>(qkv, rc, rs, qnw, qnb, knw, knb, xdet,
                                              Qp, Kp, Vt);
  attn<<<512, 256, 0, stream>>>(Qp, Kp, Vt, O0, O1, lprt);
  combine<<<4096, 256, 0, stream>>>(O0, O1, lprt, Obuf);
  gemm_bt<1, 64, 0, 2><<<512, 256, 0, stream>>>(Obuf, nullptr, Wot, bias + 3072,
                                                d_out, xdet, 4096, 1024, 1024);
}

// Round 13
// 218.192 us; speedup vs baseline: 1.0959x; 1.0959x over previous
//
#include <hip/hip_runtime.h>

typedef __attribute__((ext_vector_type(8))) __bf16 bf16x8;
typedef __attribute__((ext_vector_type(4))) float  f32x4;

#define DEV __device__ __forceinline__

DEV void async_copy16(const void* g, void* l) {
  __builtin_amdgcn_global_load_lds((const __attribute__((address_space(1))) void*)g,
                                   (__attribute__((address_space(3))) void*)l, 16, 0, 0);
}

DEV float ldf(const void* p, size_t i, int isbf) {
  if (isbf) {
    unsigned int w = ((unsigned int)((const unsigned short*)p)[i]) << 16;
    float f; __builtin_memcpy(&f, &w, 4); return f;
  }
  return ((const float*)p)[i];
}

// uniform per-block dtype probe on x's first 64 halfwords (scalar loads; all lanes agree)
DEV int detect_isbf(const unsigned short* __restrict__ x) {
  int bad = 0;
#pragma unroll
  for (int i = 0; i < 64; i++) {
    int e = (x[i] >> 7) & 0xFF;
    bad |= (e >= 0x90) ? 1 : 0;
  }
  return !bad;
}

// ---- fused prep: z<4 -> transpose weight z into bf16 [C][R]; z==4 -> x cast (fp32 only) + bias ----
__global__ __launch_bounds__(256) void prep(const void* __restrict__ Wq,
                                            const void* __restrict__ Wk,
                                            const void* __restrict__ Wv,
                                            const void* __restrict__ Wo,
                                            const void* __restrict__ x,
                                            const void* __restrict__ bq,
                                            const void* __restrict__ bk,
                                            const void* __restrict__ bv,
                                            const void* __restrict__ bo,
                                            __bf16* __restrict__ Wt,
                                            __bf16* __restrict__ Wot,
                                            __bf16* __restrict__ x_bf,
                                            float* __restrict__ bias) {
  __shared__ float tile[32][33];
  const int isbf = detect_isbf((const unsigned short*)x);
  const int tid = threadIdx.x;
  const int z = blockIdx.z;

  if (z < 4) {
    const void* in = (z == 0) ? Wq : (z == 1) ? Wk : (z == 2) ? Wv : Wo;
    __bf16* out = (z < 3) ? (Wt + (size_t)z * 1024 * 1024) : Wot;
    const int tx = tid & 31, ty = tid >> 5;
    const int r0 = blockIdx.y * 32, c0 = blockIdx.x * 32;
#pragma unroll
    for (int i = 0; i < 4; i++) {
      int r = ty + i * 8;
      tile[r][tx] = ldf(in, (size_t)(r0 + r) * 1024 + c0 + tx, isbf);
    }
    __syncthreads();
#pragma unroll
    for (int i = 0; i < 4; i++) {
      int r = ty + i * 8;
      out[(size_t)(c0 + r) * 1024 + r0 + tx] = (__bf16)tile[tx][r];
    }
  } else {
    const int id = blockIdx.y * 32 + blockIdx.x;  // 0..1023
    if (!isbf) {
#pragma unroll
      for (int j = 0; j < 4; j++) {
        int idx = id * 1024 + j * 256 + tid;
        float4 f = ((const float4*)x)[idx];
        union { __bf16 h[4]; uint2 u; } pk;
        pk.h[0] = (__bf16)f.x; pk.h[1] = (__bf16)f.y;
        pk.h[2] = (__bf16)f.z; pk.h[3] = (__bf16)f.w;
        ((uint2*)x_bf)[idx] = pk.u;
      }
    }
    if (id < 16) {
      int i = id * 256 + tid;
      if (i < 1024)      bias[i] = ldf(bq, i, isbf);
      else if (i < 2048) bias[i] = ldf(bk, i - 1024, isbf);
      else if (i < 3072) bias[i] = ldf(bv, i - 2048, isbf);
      else               bias[i] = ldf(bo, i - 3072, isbf);
    }
  }
}

// ---------------- fused QKV gemm + LN + RoPE + V-transpose ----------------
// Tile 128m x 192n; panel h = concat-channels [h*192,(h+1)*192) = one head's q|k|v.
// Wave tile: 32 rows x 192 cols (j 0..3=q, 4..7=k, 8..11=v). Epilogue does per-head
// LN (4-shfl l15 reductions), RoPE (j <-> j+2 in-lane), writes Qp/Kp directly and V
// transposed via the dead Bs LDS. Grid 512 (1-D): xcd=id&7 pins 2 head-panels/XCD.
__global__ __launch_bounds__(256, 2) void gemm_qkv(const __bf16* __restrict__ A,
                                                   const __bf16* __restrict__ Aalt,
                                                   const __bf16* __restrict__ Bt,
                                                   const float* __restrict__ bias,
                                                   const void* __restrict__ rcos,
                                                   const void* __restrict__ rsin,
                                                   const void* __restrict__ qnw,
                                                   const void* __restrict__ qnb,
                                                   const void* __restrict__ knw,
                                                   const void* __restrict__ knb,
                                                   const unsigned short* __restrict__ xdet,
                                                   __bf16* __restrict__ Qp,
                                                   __bf16* __restrict__ Kp,
                                                   __bf16* __restrict__ Vt) {
  __shared__ __align__(16) __bf16 As[128 * 64];
  __shared__ __align__(16) __bf16 Bs[192 * 64];   // reused as vt[64][132] in epilogue
  const int tid = threadIdx.x, wid = tid >> 6, lane = tid & 63;
  const int l8 = lane >> 3, l7 = lane & 7;
  const int cc = l7 ^ (l8 & 7);
  const int q4 = lane >> 4, l15 = lane & 15;

  const int xcd = blockIdx.x & 7, t = blockIdx.x >> 3;
  const int m_blk = (t & 31) * 128;
  const int h = xcd * 2 + (t >> 5);
  const int n_blk = h * 192;

  const int isbf = detect_isbf(xdet);
  const __bf16* Ap = isbf ? Aalt : A;
  const int K = 1024;

  f32x4 acc[2][12] = {};

  for (int kb = 0; kb < K; kb += 64) {
    __syncthreads();
#pragma unroll
    for (int i = 0; i < 4; i++) {
      int row = i * 32 + wid * 8 + l8;
      async_copy16(Ap + (size_t)(m_blk + row) * K + kb + cc * 8,
                   As + (i * 32 + wid * 8) * 64);
    }
#pragma unroll
    for (int i = 0; i < 6; i++) {
      int row = i * 32 + wid * 8 + l8;
      async_copy16(Bt + (size_t)(n_blk + row) * K + kb + cc * 8,
                   Bs + (i * 32 + wid * 8) * 64);
    }
    __syncthreads();
#pragma unroll
    for (int k0 = 0; k0 < 64; k0 += 32) {
      bf16x8 a[2], b[12];
#pragma unroll
      for (int i = 0; i < 2; i++) {
        int ra = wid * 32 + i * 16 + l15;
        int ba = ra * 8 + (((k0 >> 3) + q4) ^ (ra & 7));
        a[i] = *(const bf16x8*)&As[ba * 8];
      }
#pragma unroll
      for (int j = 0; j < 12; j++) {
        int rb = j * 16 + l15;
        int bb = rb * 8 + (((k0 >> 3) + q4) ^ (rb & 7));
        b[j] = *(const bf16x8*)&Bs[bb * 8];
      }
#pragma unroll
      for (int i = 0; i < 2; i++)
#pragma unroll
        for (int j = 0; j < 12; j++)
          acc[i][j] = __builtin_amdgcn_mfma_f32_16x16x32_bf16(a[i], b[j], acc[i][j], 0, 0, 0);
    }
  }

  // ---- epilogue: bias + per-head LN + RoPE + scatter ----
  float bc[12], gq[4], bq4[4], gk[4], bk4[4];
#pragma unroll
  for (int j = 0; j < 12; j++) bc[j] = bias[n_blk + j * 16 + l15];
#pragma unroll
  for (int j = 0; j < 4; j++) {
    gq[j]  = ldf(qnw, j * 16 + l15, isbf);
    bq4[j] = ldf(qnb, j * 16 + l15, isbf);
    gk[j]  = ldf(knw, j * 16 + l15, isbf);
    bk4[j] = ldf(knb, j * 16 + l15, isbf);
  }

  __syncthreads();                 // all MFMA reads of Bs done -> reuse as vt
  __bf16* vt = (__bf16*)Bs;        // [64 d][132] (pad keeps 8B align, 2-way-free writes)

#pragma unroll
  for (int i = 0; i < 2; i++) {
#pragma unroll
    for (int r = 0; r < 4; r++) {
      const int rowl = wid * 32 + i * 16 + q4 * 4 + r;
      const int m = m_blk + rowl;
      const int b = m >> 11, n = m & 2047;
      const size_t tok = (size_t)b * 2048 + n;

      float qv[4], kv[4];
#pragma unroll
      for (int j = 0; j < 4; j++) { qv[j] = acc[i][j][r] + bc[j]; kv[j] = acc[i][4 + j][r] + bc[4 + j]; }
      float sq = qv[0] + qv[1] + qv[2] + qv[3];
      float sk = kv[0] + kv[1] + kv[2] + kv[3];
#pragma unroll
      for (int mk = 1; mk < 16; mk <<= 1) { sq += __shfl_xor(sq, mk, 64); sk += __shfl_xor(sk, mk, 64); }
      float muq = sq * (1.0f / 64.0f), muk = sk * (1.0f / 64.0f);
      float vq = 0.f, vk = 0.f;
#pragma unroll
      for (int j = 0; j < 4; j++) {
        float u = qv[j] - muq; qv[j] = u; vq += u * u;
        float w = kv[j] - muk; kv[j] = w; vk += w * w;
      }
#pragma unroll
      for (int mk = 1; mk < 16; mk <<= 1) { vq += __shfl_xor(vq, mk, 64); vk += __shfl_xor(vk, mk, 64); }
      float rsq = rsqrtf(vq * (1.0f / 64.0f) + 1e-6f);
      float rsk = rsqrtf(vk * (1.0f / 64.0f) + 1e-6f);

      float qn[4], kn[4], cs[4], sn[4];
#pragma unroll
      for (int j = 0; j < 4; j++) {
        qn[j] = qv[j] * rsq * gq[j] + bq4[j];
        kn[j] = kv[j] * rsk * gk[j] + bk4[j];
        cs[j] = ldf(rcos, tok * 64 + j * 16 + l15, isbf);
        sn[j] = ldf(rsin, tok * 64 + j * 16 + l15, isbf);
      }
      const size_t ob = ((size_t)(b * 16 + h) * 2048 + n) * 64;
#pragma unroll
      for (int j = 0; j < 2; j++) {
        float qr0 = qn[j] * cs[j] - qn[j + 2] * sn[j];          // d < 32: -x[d+32]*sin
        float qr1 = qn[j + 2] * cs[j + 2] + qn[j] * sn[j + 2];  // d >= 32: +x[d-32]*sin
        float kr0 = kn[j] * cs[j] - kn[j + 2] * sn[j];
        float kr1 = kn[j + 2] * cs[j + 2] + kn[j] * sn[j + 2];
        Qp[ob + j * 16 + l15]       = (__bf16)(qr0 * 0.1803368801111204f);  // 0.125*log2(e)
        Qp[ob + (j + 2) * 16 + l15] = (__bf16)(qr1 * 0.1803368801111204f);
        Kp[ob + j * 16 + l15]       = (__bf16)kr0;
        Kp[ob + (j + 2) * 16 + l15] = (__bf16)kr1;
      }
#pragma unroll
      for (int j = 0; j < 4; j++) {
        int d = j * 16 + l15;
        vt[d * 132 + rowl] = (__bf16)(acc[i][8 + j][r] + bc[8 + j]);
      }
    }
  }
  __syncthreads();
  // write Vt[bh][d][n] coalesced: thread -> d = tid>>2, quarter qt = tid&3 (32 tokens)
  {
    const int d = tid >> 2, qt = tid & 3;
    const int b0 = m_blk >> 11, n0 = m_blk & 2047;  // 128-row tile never straddles batch
    size_t gbase = ((size_t)(b0 * 16 + h) * 64 + d) * 2048 + n0 + qt * 32;
#pragma unroll
    for (int u = 0; u < 8; u++)
      *(uint2*)&Vt[gbase + u * 4] = *(const uint2*)&vt[d * 132 + qt * 32 + u * 4];
  }
}

// ---------------- GEMM (out-proj): C[M,NT] = A[M,K] @ Bt[N,K]^T + bias ----------------
template <int DYN, int NT, int NPX>
__global__ __launch_bounds__(256, 3) void gemm_bt(const __bf16* __restrict__ A,
                                                  const __bf16* __restrict__ Bt,
                                                  const float* __restrict__ bias,
                                                  void* __restrict__ Cout,
                                                  const unsigned short* __restrict__ xdet,
                                                  int M, int N, int K) {
  constexpr int WN = NT / 2;
  constexpr int JB = WN / 16;
  constexpr int NR = NT / 32;
  __shared__ __align__(16) __bf16 As[128 * 64];
  __shared__ __align__(16) __bf16 Bs[NT * 64];
  const int tid = threadIdx.x;
  const int wid = tid >> 6, lane = tid & 63;
  const int xcd = blockIdx.x & 7, t = blockIdx.x >> 3;
  const int m_blk = (t & 31) * 128;
  const int n_blk = (xcd * NPX + (t >> 5)) * NT;
  const int wm = (wid & 1) * 64, wn = (wid >> 1) * WN;
  const int l8 = lane >> 3, l7 = lane & 7;
  const int cc = l7 ^ (l8 & 7);
  const int q4 = lane >> 4, l15 = lane & 15;

  int isbf = 1;
  if (DYN) isbf = detect_isbf(xdet);

  f32x4 acc[4][JB] = {};

  for (int kb = 0; kb < K; kb += 64) {
    __syncthreads();
#pragma unroll
    for (int i = 0; i < 4; i++) {
      int row = i * 32 + wid * 8 + l8;
      async_copy16(A + (size_t)(m_blk + row) * K + kb + cc * 8,
                   As + (i * 32 + wid * 8) * 64);
    }
#pragma unroll
    for (int i = 0; i < NR; i++) {
      int row = i * 32 + wid * 8 + l8;
      async_copy16(Bt + (size_t)(n_blk + row) * K + kb + cc * 8,
                   Bs + (i * 32 + wid * 8) * 64);
    }
    __syncthreads();
#pragma unroll
    for (int k0 = 0; k0 < 64; k0 += 32) {
      bf16x8 a[4], b[JB];
#pragma unroll
      for (int i = 0; i < 4; i++) {
        int ra = wm + i * 16 + l15;
        int ba = ra * 8 + (((k0 >> 3) + q4) ^ (ra & 7));
        a[i] = *(const bf16x8*)&As[ba * 8];
      }
#pragma unroll
      for (int j = 0; j < JB; j++) {
        int rb = wn + j * 16 + l15;
        int bb = rb * 8 + (((k0 >> 3) + q4) ^ (rb & 7));
        b[j] = *(const bf16x8*)&Bs[bb * 8];
      }
#pragma unroll
      for (int i = 0; i < 4; i++)
#pragma unroll
        for (int j = 0; j < JB; j++)
          acc[i][j] = __builtin_amdgcn_mfma_f32_16x16x32_bf16(a[i], b[j], acc[i][j], 0, 0, 0);
    }
  }

  float bcol[JB];
#pragma unroll
  for (int j = 0; j < JB; j++) bcol[j] = bias[n_blk + wn + j * 16 + l15];
#pragma unroll
  for (int i = 0; i < 4; i++)
#pragma unroll
    for (int j = 0; j < JB; j++) {
      int col = n_blk + wn + j * 16 + l15;
#pragma unroll
      for (int r = 0; r < 4; r++) {
        int row = m_blk + wm + i * 16 + q4 * 4 + r;
        float v = acc[i][j][r] + bcol[j];
        size_t idx = (size_t)row * N + col;
        if (DYN && !isbf) ((float*)Cout)[idx] = v;
        else              ((__bf16*)Cout)[idx] = (__bf16)v;
      }
    }
}

// ---------------- flash attention: K-split x2, KT=32, XCD-swizzled (round-11 proven) ----------------
__global__ __launch_bounds__(256, 4) void attn(const __bf16* __restrict__ Qp,
                                               const __bf16* __restrict__ Kp,
                                               const __bf16* __restrict__ Vt,
                                               float* __restrict__ O0,
                                               float* __restrict__ O1,
                                               float* __restrict__ lpart) {
  __shared__ __align__(16) __bf16 sK[2][2048];
  __shared__ __align__(16) __bf16 sV[2][2048];
  __shared__ __align__(16) __bf16 sP[4][1024];

  const int tid = threadIdx.x, wid = tid >> 6, lane = tid & 63;
  const int q4 = lane >> 4, l15 = lane & 15;
  const int lin = blockIdx.x;
  const int xcd = lin & 7;
  const int rest = lin >> 3;
  const int qblk = rest & 15;
  const int g = (rest >> 4) * 8 + xcd;   // 0..63
  const int bh = g & 31, split = g >> 5;
  const int q0w = qblk * 128 + wid * 32;
  const int kt0 = split * 1024;
  const __bf16* Qb = Qp + (size_t)bh * 2048 * 64;
  const __bf16* Kb = Kp + (size_t)bh * 2048 * 64;
  const __bf16* Vb = Vt + (size_t)bh * 64 * 2048;
  float* Op = split ? O1 : O0;
  __bf16* sPw = &sP[wid][0];
  const int pbase = (q4 >> 1) * 128 + l15 * 8 + (q4 & 1) * 4;

  bf16x8 qf[2][2];
#pragma unroll
  for (int qs = 0; qs < 2; qs++)
#pragma unroll
    for (int c = 0; c < 2; c++)
      qf[qs][c] = *(const bf16x8*)&Qb[(size_t)(q0w + qs * 16 + l15) * 64 + c * 32 + q4 * 8];

  bf16x8 ones8;
#pragma unroll
  for (int i = 0; i < 8; i++) ones8[i] = (__bf16)1.0f;

  f32x4 o[2][4] = {};
  f32x4 l_acc[2] = {};

#define STAGE(kt, bf)                                                                    \
  do {                                                                                   \
    async_copy16(Kb + (size_t)((kt) + (wid >> 1) * 16 + l15) * 64 + (wid & 1) * 32 + q4 * 8, \
                 &sK[bf][wid * 512]);                                                    \
    async_copy16(Vb + (size_t)(wid * 16 + l15) * 2048 + (kt) + q4 * 8,                   \
                 &sV[bf][wid * 512]);                                                    \
  } while (0)

  STAGE(kt0, 0);

  for (int it = 0; it < 32; ++it) {
    const int buf = it & 1;
    __syncthreads();
    if (it < 31) STAGE(kt0 + (it + 1) * 32, buf ^ 1);

    bf16x8 ak[2][2];
#pragma unroll
    for (int ks = 0; ks < 2; ks++)
#pragma unroll
      for (int c = 0; c < 2; c++)
        ak[ks][c] = *(const bf16x8*)&sK[buf][((ks * 2 + c) * 64 + lane) * 8];
    f32x4 sc[2][2];
#pragma unroll
    for (int qs = 0; qs < 2; qs++)
#pragma unroll
      for (int ks = 0; ks < 2; ks++) {
        f32x4 z = {0.f, 0.f, 0.f, 0.f};
        z = __builtin_amdgcn_mfma_f32_16x16x32_bf16(ak[ks][0], qf[qs][0], z, 0, 0, 0);
        z = __builtin_amdgcn_mfma_f32_16x16x32_bf16(ak[ks][1], qf[qs][1], z, 0, 0, 0);
        sc[qs][ks] = z;
      }

#pragma unroll
    for (int qs = 0; qs < 2; qs++)
#pragma unroll
      for (int ks = 0; ks < 2; ks++) {
        uint2 pk;
        {
          float p0 = __builtin_amdgcn_exp2f(sc[qs][ks][0]);
          float p1 = __builtin_amdgcn_exp2f(sc[qs][ks][1]);
          pk.x = __builtin_amdgcn_perm(__builtin_bit_cast(unsigned int, p1),
                                       __builtin_bit_cast(unsigned int, p0), 0x07060302u);
          float p2 = __builtin_amdgcn_exp2f(sc[qs][ks][2]);
          float p3 = __builtin_amdgcn_exp2f(sc[qs][ks][3]);
          pk.y = __builtin_amdgcn_perm(__builtin_bit_cast(unsigned int, p3),
                                       __builtin_bit_cast(unsigned int, p2), 0x07060302u);
        }
        *(uint2*)&sPw[qs * 512 + ks * 256 + pbase] = pk;
      }
    asm volatile("s_waitcnt lgkmcnt(0)" ::: "memory");

    bf16x8 pb[2];
#pragma unroll
    for (int qs = 0; qs < 2; qs++)
      pb[qs] = *(const bf16x8*)&sPw[(qs * 64 + lane) * 8];
#pragma unroll
    for (int qs = 0; qs < 2; qs++)
      l_acc[qs] = __builtin_amdgcn_mfma_f32_16x16x32_bf16(ones8, pb[qs], l_acc[qs], 0, 0, 0);
#pragma unroll
    for (int ds = 0; ds < 4; ds++) {
      bf16x8 av = *(const bf16x8*)&sV[buf][(ds * 64 + lane) * 8];
#pragma unroll
      for (int qs = 0; qs < 2; qs++)
        o[qs][ds] = __builtin_amdgcn_mfma_f32_16x16x32_bf16(av, pb[qs], o[qs][ds], 0, 0, 0);
    }
  }
#undef STAGE

#pragma unroll
  for (int qs = 0; qs < 2; qs++) {
    const int q = q0w + qs * 16 + l15;
    if (q4 == 0) lpart[(size_t)(split * 32 + bh) * 2048 + q] = l_acc[qs][0];
    size_t base = ((size_t)bh * 2048 + q) * 64;
#pragma unroll
    for (int ds = 0; ds < 4; ds++)
      *(f32x4*)&Op[base + ds * 16 + q4 * 4] = o[qs][ds];
  }
}

// ---------------- combine: Obuf = (O0+O1) / (l0+l1), bf16 [b][q][h*64+d] ----------------
__global__ __launch_bounds__(256) void combine(const float* __restrict__ O0,
                                               const float* __restrict__ O1,
                                               const float* __restrict__ lpart,
                                               __bf16* __restrict__ Obuf) {
  const int idx = blockIdx.x * 256 + threadIdx.x;
  const int d4 = idx & 15, q = (idx >> 4) & 2047, bh = idx >> 15;
  const int b = bh >> 4, h = bh & 15;
  const size_t po = ((size_t)bh * 2048 + q) * 64 + d4 * 4;
  f32x4 a = *(const f32x4*)&O0[po];
  f32x4 c = *(const f32x4*)&O1[po];
  float l = lpart[(size_t)bh * 2048 + q] + lpart[(size_t)(32 + bh) * 2048 + q];
  float rl = 1.0f / l;
  union { __bf16 h4[4]; uint2 u; } pk;
#pragma unroll
  for (int r = 0; r < 4; r++) pk.h4[r] = (__bf16)((a[r] + c[r]) * rl);
  *(uint2*)&Obuf[((size_t)(b * 2048 + q)) * 1024 + h * 64 + d4 * 4] = pk.u;
}

extern "C" void kernel_launch(void* const* d_in, const int* in_sizes, int n_in,
                              void* d_out, int out_size, void* d_ws, size_t ws_size,
                              hipStream_t stream) {
  const void* x   = d_in[0];
  const void* rc  = d_in[1];
  const void* rs  = d_in[2];
  const void* Wq  = d_in[3];
  const void* bq  = d_in[4];
  const void* Wk  = d_in[5];
  const void* bk  = d_in[6];
  const void* Wv  = d_in[7];
  const void* bv  = d_in[8];
  const void* qnw = d_in[9];
  const void* qnb = d_in[10];
  const void* knw = d_in[11];
  const void* knb = d_in[12];
  const void* Wo  = d_in[13];
  const void* bo  = d_in[14];
  const unsigned short* xdet = (const unsigned short*)x;

  // temporal aliasing:
  //  [0, 16M)      O0 fp32 (attn -> combine)
  //  [16M, 32M)    O1 fp32; x_bf (prep -> gemm_qkv, fp32 path) at 25.1M dies before attn
  //  [33.5M, 41.9M) Qp (gemm_qkv -> attn), then Obuf (combine -> gemm1)
  char* ws = (char*)d_ws;
  float*  O0    = (float*)ws;
  float*  O1    = (float*)(ws + 16777216);
  __bf16* x_bf  = (__bf16*)(ws + 25165824);
  __bf16* Qp    = (__bf16*)(ws + 33554432);
  __bf16* Obuf  = (__bf16*)(ws + 33554432);
  __bf16* Kp    = (__bf16*)(ws + 41943040);
  __bf16* Vt    = (__bf16*)(ws + 50331648);
  __bf16* Wt    = (__bf16*)(ws + 58720256);   // [3072][1024] 6 MB
  __bf16* Wot   = (__bf16*)(ws + 65011712);   // [1024][1024] 2 MB
  float*  bias  = (float*)(ws + 67108864);    // [4096]
  float*  lprt  = (float*)(ws + 67125248);    // [2][32][2048] fp32

  prep<<<dim3(32, 32, 5), 256, 0, stream>>>(Wq, Wk, Wv, Wo, x, bq, bk, bv, bo,
                                            Wt, Wot, x_bf, bias);
  gemm_qkv<<<512, 256, 0, stream>>>(x_bf, (const __bf16*)x, Wt, bias, rc, rs,
                                    qnw, qnb, knw, knb, xdet, Qp, Kp, Vt);
  attn<<<1024, 256, 0, stream>>>(Qp, Kp, Vt, O0, O1, lprt);
  combine<<<4096, 256, 0, stream>>>(O0, O1, lprt, Obuf);
  gemm_bt<1, 64, 2><<<512, 256, 0, stream>>>(Obuf, Wot, bias + 3072,
                                             d_out, xdet, 4096, 1024, 1024);
}

// Round 15
// 217.827 us; speedup vs baseline: 1.0977x; 1.0017x over previous
//
#include <hip/hip_runtime.h>

typedef __attribute__((ext_vector_type(8))) __bf16 bf16x8;
typedef __attribute__((ext_vector_type(4))) float  f32x4;

#define DEV __device__ __forceinline__

DEV void async_copy16(const void* g, void* l) {
  __builtin_amdgcn_global_load_lds((const __attribute__((address_space(1))) void*)g,
                                   (__attribute__((address_space(3))) void*)l, 16, 0, 0);
}

DEV float ldf(const void* p, size_t i, int isbf) {
  if (isbf) {
    unsigned int w = ((unsigned int)((const unsigned short*)p)[i]) << 16;
    float f; __builtin_memcpy(&f, &w, 4); return f;
  }
  return ((const float*)p)[i];
}

// uniform per-block dtype probe on x's first 64 halfwords (scalar loads; all lanes agree)
DEV int detect_isbf(const unsigned short* __restrict__ x) {
  int bad = 0;
#pragma unroll
  for (int i = 0; i < 64; i++) {
    int e = (x[i] >> 7) & 0xFF;
    bad |= (e >= 0x90) ? 1 : 0;
  }
  return !bad;
}

// ---- fused prep: z<4 -> transpose weight z into bf16 [C][R]; z==4 -> x cast (fp32 only) + bias ----
__global__ __launch_bounds__(256) void prep(const void* __restrict__ Wq,
                                            const void* __restrict__ Wk,
                                            const void* __restrict__ Wv,
                                            const void* __restrict__ Wo,
                                            const void* __restrict__ x,
                                            const void* __restrict__ bq,
                                            const void* __restrict__ bk,
                                            const void* __restrict__ bv,
                                            const void* __restrict__ bo,
                                            __bf16* __restrict__ Wt,
                                            __bf16* __restrict__ Wot,
                                            __bf16* __restrict__ x_bf,
                                            float* __restrict__ bias) {
  __shared__ float tile[32][33];
  const int isbf = detect_isbf((const unsigned short*)x);
  const int tid = threadIdx.x;
  const int z = blockIdx.z;

  if (z < 4) {
    const void* in = (z == 0) ? Wq : (z == 1) ? Wk : (z == 2) ? Wv : Wo;
    __bf16* out = (z < 3) ? (Wt + (size_t)z * 1024 * 1024) : Wot;
    const int tx = tid & 31, ty = tid >> 5;
    const int r0 = blockIdx.y * 32, c0 = blockIdx.x * 32;
#pragma unroll
    for (int i = 0; i < 4; i++) {
      int r = ty + i * 8;
      tile[r][tx] = ldf(in, (size_t)(r0 + r) * 1024 + c0 + tx, isbf);
    }
    __syncthreads();
#pragma unroll
    for (int i = 0; i < 4; i++) {
      int r = ty + i * 8;
      out[(size_t)(c0 + r) * 1024 + r0 + tx] = (__bf16)tile[tx][r];
    }
  } else {
    const int id = blockIdx.y * 32 + blockIdx.x;  // 0..1023
    if (!isbf) {
#pragma unroll
      for (int j = 0; j < 4; j++) {
        int idx = id * 1024 + j * 256 + tid;
        float4 f = ((const float4*)x)[idx];
        union { __bf16 h[4]; uint2 u; } pk;
        pk.h[0] = (__bf16)f.x; pk.h[1] = (__bf16)f.y;
        pk.h[2] = (__bf16)f.z; pk.h[3] = (__bf16)f.w;
        ((uint2*)x_bf)[idx] = pk.u;
      }
    }
    if (id < 16) {
      int i = id * 256 + tid;
      if (i < 1024)      bias[i] = ldf(bq, i, isbf);
      else if (i < 2048) bias[i] = ldf(bk, i - 1024, isbf);
      else if (i < 3072) bias[i] = ldf(bv, i - 2048, isbf);
      else               bias[i] = ldf(bo, i - 3072, isbf);
    }
  }
}

// ---------------- fused QKV gemm + LN + RoPE + V-transpose (round-13 proven) ----------------
// Tile 128m x 192n; panel h = concat-channels [h*192,(h+1)*192) = one head's q|k|v.
// Wave tile: 32 rows x 192 cols (j 0..3=q, 4..7=k, 8..11=v). Epilogue does per-head
// LN (4-shfl l15 reductions), RoPE (j <-> j+2 in-lane), writes Qp/Kp directly and V
// transposed via the dead Bs LDS. Grid 512 (1-D): xcd=id&7 pins 2 head-panels/XCD.
__global__ __launch_bounds__(256, 2) void gemm_qkv(const __bf16* __restrict__ A,
                                                   const __bf16* __restrict__ Aalt,
                                                   const __bf16* __restrict__ Bt,
                                                   const float* __restrict__ bias,
                                                   const void* __restrict__ rcos,
                                                   const void* __restrict__ rsin,
                                                   const void* __restrict__ qnw,
                                                   const void* __restrict__ qnb,
                                                   const void* __restrict__ knw,
                                                   const void* __restrict__ knb,
                                                   const unsigned short* __restrict__ xdet,
                                                   __bf16* __restrict__ Qp,
                                                   __bf16* __restrict__ Kp,
                                                   __bf16* __restrict__ Vt) {
  __shared__ __align__(16) __bf16 As[128 * 64];
  __shared__ __align__(16) __bf16 Bs[192 * 64];   // reused as vt[64][132] in epilogue
  const int tid = threadIdx.x, wid = tid >> 6, lane = tid & 63;
  const int l8 = lane >> 3, l7 = lane & 7;
  const int cc = l7 ^ (l8 & 7);
  const int q4 = lane >> 4, l15 = lane & 15;

  const int xcd = blockIdx.x & 7, t = blockIdx.x >> 3;
  const int m_blk = (t & 31) * 128;
  const int h = xcd * 2 + (t >> 5);
  const int n_blk = h * 192;

  const int isbf = detect_isbf(xdet);
  const __bf16* Ap = isbf ? Aalt : A;
  const int K = 1024;

  f32x4 acc[2][12] = {};

  for (int kb = 0; kb < K; kb += 64) {
    __syncthreads();
#pragma unroll
    for (int i = 0; i < 4; i++) {
      int row = i * 32 + wid * 8 + l8;
      async_copy16(Ap + (size_t)(m_blk + row) * K + kb + cc * 8,
                   As + (i * 32 + wid * 8) * 64);
    }
#pragma unroll
    for (int i = 0; i < 6; i++) {
      int row = i * 32 + wid * 8 + l8;
      async_copy16(Bt + (size_t)(n_blk + row) * K + kb + cc * 8,
                   Bs + (i * 32 + wid * 8) * 64);
    }
    __syncthreads();
#pragma unroll
    for (int k0 = 0; k0 < 64; k0 += 32) {
      bf16x8 a[2], b[12];
#pragma unroll
      for (int i = 0; i < 2; i++) {
        int ra = wid * 32 + i * 16 + l15;
        int ba = ra * 8 + (((k0 >> 3) + q4) ^ (ra & 7));
        a[i] = *(const bf16x8*)&As[ba * 8];
      }
#pragma unroll
      for (int j = 0; j < 12; j++) {
        int rb = j * 16 + l15;
        int bb = rb * 8 + (((k0 >> 3) + q4) ^ (rb & 7));
        b[j] = *(const bf16x8*)&Bs[bb * 8];
      }
#pragma unroll
      for (int i = 0; i < 2; i++)
#pragma unroll
        for (int j = 0; j < 12; j++)
          acc[i][j] = __builtin_amdgcn_mfma_f32_16x16x32_bf16(a[i], b[j], acc[i][j], 0, 0, 0);
    }
  }

  // ---- epilogue: bias + per-head LN + RoPE + scatter ----
  float bc[12], gq[4], bq4[4], gk[4], bk4[4];
#pragma unroll
  for (int j = 0; j < 12; j++) bc[j] = bias[n_blk + j * 16 + l15];
#pragma unroll
  for (int j = 0; j < 4; j++) {
    gq[j]  = ldf(qnw, j * 16 + l15, isbf);
    bq4[j] = ldf(qnb, j * 16 + l15, isbf);
    gk[j]  = ldf(knw, j * 16 + l15, isbf);
    bk4[j] = ldf(knb, j * 16 + l15, isbf);
  }

  __syncthreads();                 // all MFMA reads of Bs done -> reuse as vt
  __bf16* vt = (__bf16*)Bs;        // [64 d][132]

#pragma unroll
  for (int i = 0; i < 2; i++) {
#pragma unroll
    for (int r = 0; r < 4; r++) {
      const int rowl = wid * 32 + i * 16 + q4 * 4 + r;
      const int m = m_blk + rowl;
      const int b = m >> 11, n = m & 2047;
      const size_t tok = (size_t)b * 2048 + n;

      float qv[4], kv[4];
#pragma unroll
      for (int j = 0; j < 4; j++) { qv[j] = acc[i][j][r] + bc[j]; kv[j] = acc[i][4 + j][r] + bc[4 + j]; }
      float sq = qv[0] + qv[1] + qv[2] + qv[3];
      float sk = kv[0] + kv[1] + kv[2] + kv[3];
#pragma unroll
      for (int mk = 1; mk < 16; mk <<= 1) { sq += __shfl_xor(sq, mk, 64); sk += __shfl_xor(sk, mk, 64); }
      float muq = sq * (1.0f / 64.0f), muk = sk * (1.0f / 64.0f);
      float vq = 0.f, vk = 0.f;
#pragma unroll
      for (int j = 0; j < 4; j++) {
        float u = qv[j] - muq; qv[j] = u; vq += u * u;
        float w = kv[j] - muk; kv[j] = w; vk += w * w;
      }
#pragma unroll
      for (int mk = 1; mk < 16; mk <<= 1) { vq += __shfl_xor(vq, mk, 64); vk += __shfl_xor(vk, mk, 64); }
      float rsq = rsqrtf(vq * (1.0f / 64.0f) + 1e-6f);
      float rsk = rsqrtf(vk * (1.0f / 64.0f) + 1e-6f);

      float qn[4], kn[4], cs[4], sn[4];
#pragma unroll
      for (int j = 0; j < 4; j++) {
        qn[j] = qv[j] * rsq * gq[j] + bq4[j];
        kn[j] = kv[j] * rsk * gk[j] + bk4[j];
        cs[j] = ldf(rcos, tok * 64 + j * 16 + l15, isbf);
        sn[j] = ldf(rsin, tok * 64 + j * 16 + l15, isbf);
      }
      const size_t ob = ((size_t)(b * 16 + h) * 2048 + n) * 64;
#pragma unroll
      for (int j = 0; j < 2; j++) {
        float qr0 = qn[j] * cs[j] - qn[j + 2] * sn[j];          // d < 32: -x[d+32]*sin
        float qr1 = qn[j + 2] * cs[j + 2] + qn[j] * sn[j + 2];  // d >= 32: +x[d-32]*sin
        float kr0 = kn[j] * cs[j] - kn[j + 2] * sn[j];
        float kr1 = kn[j + 2] * cs[j + 2] + kn[j] * sn[j + 2];
        Qp[ob + j * 16 + l15]       = (__bf16)(qr0 * 0.1803368801111204f);  // 0.125*log2(e)
        Qp[ob + (j + 2) * 16 + l15] = (__bf16)(qr1 * 0.1803368801111204f);
        Kp[ob + j * 16 + l15]       = (__bf16)kr0;
        Kp[ob + (j + 2) * 16 + l15] = (__bf16)kr1;
      }
#pragma unroll
      for (int j = 0; j < 4; j++) {
        int d = j * 16 + l15;
        vt[d * 132 + rowl] = (__bf16)(acc[i][8 + j][r] + bc[8 + j]);
      }
    }
  }
  __syncthreads();
  // write Vt[bh][d][n] coalesced: thread -> d = tid>>2, quarter qt = tid&3 (32 tokens)
  {
    const int d = tid >> 2, qt = tid & 3;
    const int b0 = m_blk >> 11, n0 = m_blk & 2047;  // 128-row tile never straddles batch
    size_t gbase = ((size_t)(b0 * 16 + h) * 64 + d) * 2048 + n0 + qt * 32;
#pragma unroll
    for (int u = 0; u < 8; u++)
      *(uint2*)&Vt[gbase + u * 4] = *(const uint2*)&vt[d * 132 + qt * 32 + u * 4];
  }
}

// ---------------- GEMM (out-proj): C[M,NT] = A[M,K] @ Bt[N,K]^T + bias ----------------
template <int DYN, int NT, int NPX>
__global__ __launch_bounds__(256, 3) void gemm_bt(const __bf16* __restrict__ A,
                                                  const __bf16* __restrict__ Bt,
                                                  const float* __restrict__ bias,
                                                  void* __restrict__ Cout,
                                                  const unsigned short* __restrict__ xdet,
                                                  int M, int N, int K) {
  constexpr int WN = NT / 2;
  constexpr int JB = WN / 16;
  constexpr int NR = NT / 32;
  __shared__ __align__(16) __bf16 As[128 * 64];
  __shared__ __align__(16) __bf16 Bs[NT * 64];
  const int tid = threadIdx.x;
  const int wid = tid >> 6, lane = tid & 63;
  const int xcd = blockIdx.x & 7, t = blockIdx.x >> 3;
  const int m_blk = (t & 31) * 128;
  const int n_blk = (xcd * NPX + (t >> 5)) * NT;
  const int wm = (wid & 1) * 64, wn = (wid >> 1) * WN;
  const int l8 = lane >> 3, l7 = lane & 7;
  const int cc = l7 ^ (l8 & 7);
  const int q4 = lane >> 4, l15 = lane & 15;

  int isbf = 1;
  if (DYN) isbf = detect_isbf(xdet);

  f32x4 acc[4][JB] = {};

  for (int kb = 0; kb < K; kb += 64) {
    __syncthreads();
#pragma unroll
    for (int i = 0; i < 4; i++) {
      int row = i * 32 + wid * 8 + l8;
      async_copy16(A + (size_t)(m_blk + row) * K + kb + cc * 8,
                   As + (i * 32 + wid * 8) * 64);
    }
#pragma unroll
    for (int i = 0; i < NR; i++) {
      int row = i * 32 + wid * 8 + l8;
      async_copy16(Bt + (size_t)(n_blk + row) * K + kb + cc * 8,
                   Bs + (i * 32 + wid * 8) * 64);
    }
    __syncthreads();
#pragma unroll
    for (int k0 = 0; k0 < 64; k0 += 32) {
      bf16x8 a[4], b[JB];
#pragma unroll
      for (int i = 0; i < 4; i++) {
        int ra = wm + i * 16 + l15;
        int ba = ra * 8 + (((k0 >> 3) + q4) ^ (ra & 7));
        a[i] = *(const bf16x8*)&As[ba * 8];
      }
#pragma unroll
      for (int j = 0; j < JB; j++) {
        int rb = wn + j * 16 + l15;
        int bb = rb * 8 + (((k0 >> 3) + q4) ^ (rb & 7));
        b[j] = *(const bf16x8*)&Bs[bb * 8];
      }
#pragma unroll
      for (int i = 0; i < 4; i++)
#pragma unroll
        for (int j = 0; j < JB; j++)
          acc[i][j] = __builtin_amdgcn_mfma_f32_16x16x32_bf16(a[i], b[j], acc[i][j], 0, 0, 0);
    }
  }

  float bcol[JB];
#pragma unroll
  for (int j = 0; j < JB; j++) bcol[j] = bias[n_blk + wn + j * 16 + l15];
#pragma unroll
  for (int i = 0; i < 4; i++)
#pragma unroll
    for (int j = 0; j < JB; j++) {
      int col = n_blk + wn + j * 16 + l15;
#pragma unroll
      for (int r = 0; r < 4; r++) {
        int row = m_blk + wm + i * 16 + q4 * 4 + r;
        float v = acc[i][j][r] + bcol[j];
        size_t idx = (size_t)row * N + col;
        if (DYN && !isbf) ((float*)Cout)[idx] = v;
        else              ((__bf16*)Cout)[idx] = (__bf16)v;
      }
    }
}

// ---------------- flash attention: K-split x2, KT=32, XCD-swizzled (round-11 proven) ----------------
__global__ __launch_bounds__(256, 4) void attn(const __bf16* __restrict__ Qp,
                                               const __bf16* __restrict__ Kp,
                                               const __bf16* __restrict__ Vt,
                                               float* __restrict__ O0,
                                               float* __restrict__ O1,
                                               float* __restrict__ lpart) {
  __shared__ __align__(16) __bf16 sK[2][2048];
  __shared__ __align__(16) __bf16 sV[2][2048];
  __shared__ __align__(16) __bf16 sP[4][1024];

  const int tid = threadIdx.x, wid = tid >> 6, lane = tid & 63;
  const int q4 = lane >> 4, l15 = lane & 15;
  const int lin = blockIdx.x;
  const int xcd = lin & 7;
  const int rest = lin >> 3;
  const int qblk = rest & 15;
  const int g = (rest >> 4) * 8 + xcd;   // 0..63
  const int bh = g & 31, split = g >> 5;
  const int q0w = qblk * 128 + wid * 32;
  const int kt0 = split * 1024;
  const __bf16* Qb = Qp + (size_t)bh * 2048 * 64;
  const __bf16* Kb = Kp + (size_t)bh * 2048 * 64;
  const __bf16* Vb = Vt + (size_t)bh * 64 * 2048;
  float* Op = split ? O1 : O0;
  __bf16* sPw = &sP[wid][0];
  const int pbase = (q4 >> 1) * 128 + l15 * 8 + (q4 & 1) * 4;

  bf16x8 qf[2][2];
#pragma unroll
  for (int qs = 0; qs < 2; qs++)
#pragma unroll
    for (int c = 0; c < 2; c++)
      qf[qs][c] = *(const bf16x8*)&Qb[(size_t)(q0w + qs * 16 + l15) * 64 + c * 32 + q4 * 8];

  bf16x8 ones8;
#pragma unroll
  for (int i = 0; i < 8; i++) ones8[i] = (__bf16)1.0f;

  f32x4 o[2][4] = {};
  f32x4 l_acc[2] = {};

#define STAGE(kt, bf)                                                                    \
  do {                                                                                   \
    async_copy16(Kb + (size_t)((kt) + (wid >> 1) * 16 + l15) * 64 + (wid & 1) * 32 + q4 * 8, \
                 &sK[bf][wid * 512]);                                                    \
    async_copy16(Vb + (size_t)(wid * 16 + l15) * 2048 + (kt) + q4 * 8,                   \
                 &sV[bf][wid * 512]);                                                    \
  } while (0)

  STAGE(kt0, 0);

  for (int it = 0; it < 32; ++it) {
    const int buf = it & 1;
    __syncthreads();
    if (it < 31) STAGE(kt0 + (it + 1) * 32, buf ^ 1);

    bf16x8 ak[2][2];
#pragma unroll
    for (int ks = 0; ks < 2; ks++)
#pragma unroll
      for (int c = 0; c < 2; c++)
        ak[ks][c] = *(const bf16x8*)&sK[buf][((ks * 2 + c) * 64 + lane) * 8];
    f32x4 sc[2][2];
#pragma unroll
    for (int qs = 0; qs < 2; qs++)
#pragma unroll
      for (int ks = 0; ks < 2; ks++) {
        f32x4 z = {0.f, 0.f, 0.f, 0.f};
        z = __builtin_amdgcn_mfma_f32_16x16x32_bf16(ak[ks][0], qf[qs][0], z, 0, 0, 0);
        z = __builtin_amdgcn_mfma_f32_16x16x32_bf16(ak[ks][1], qf[qs][1], z, 0, 0, 0);
        sc[qs][ks] = z;
      }

#pragma unroll
    for (int qs = 0; qs < 2; qs++)
#pragma unroll
      for (int ks = 0; ks < 2; ks++) {
        uint2 pk;
        {
          float p0 = __builtin_amdgcn_exp2f(sc[qs][ks][0]);
          float p1 = __builtin_amdgcn_exp2f(sc[qs][ks][1]);
          pk.x = __builtin_amdgcn_perm(__builtin_bit_cast(unsigned int, p1),
                                       __builtin_bit_cast(unsigned int, p0), 0x07060302u);
          float p2 = __builtin_amdgcn_exp2f(sc[qs][ks][2]);
          float p3 = __builtin_amdgcn_exp2f(sc[qs][ks][3]);
          pk.y = __builtin_amdgcn_perm(__builtin_bit_cast(unsigned int, p3),
                                       __builtin_bit_cast(unsigned int, p2), 0x07060302u);
        }
        *(uint2*)&sPw[qs * 512 + ks * 256 + pbase] = pk;
      }
    asm volatile("s_waitcnt lgkmcnt(0)" ::: "memory");

    bf16x8 pb[2];
#pragma unroll
    for (int qs = 0; qs < 2; qs++)
      pb[qs] = *(const bf16x8*)&sPw[(qs * 64 + lane) * 8];
#pragma unroll
    for (int qs = 0; qs < 2; qs++)
      l_acc[qs] = __builtin_amdgcn_mfma_f32_16x16x32_bf16(ones8, pb[qs], l_acc[qs], 0, 0, 0);
#pragma unroll
    for (int ds = 0; ds < 4; ds++) {
      bf16x8 av = *(const bf16x8*)&sV[buf][(ds * 64 + lane) * 8];
#pragma unroll
      for (int qs = 0; qs < 2; qs++)
        o[qs][ds] = __builtin_amdgcn_mfma_f32_16x16x32_bf16(av, pb[qs], o[qs][ds], 0, 0, 0);
    }
  }
#undef STAGE

#pragma unroll
  for (int qs = 0; qs < 2; qs++) {
    const int q = q0w + qs * 16 + l15;
    if (q4 == 0) lpart[(size_t)(split * 32 + bh) * 2048 + q] = l_acc[qs][0];
    size_t base = ((size_t)bh * 2048 + q) * 64;
#pragma unroll
    for (int ds = 0; ds < 4; ds++)
      *(f32x4*)&Op[base + ds * 16 + q4 * 4] = o[qs][ds];
  }
}

// ---------------- combine: Obuf = (O0+O1) / (l0+l1), bf16 [b][q][h*64+d], 8 d/thread ----------------
__global__ __launch_bounds__(256) void combine(const float* __restrict__ O0,
                                               const float* __restrict__ O1,
                                               const float* __restrict__ lpart,
                                               __bf16* __restrict__ Obuf) {
  const int idx = blockIdx.x * 256 + threadIdx.x;  // 524288 threads x 8 d
  const int d8 = idx & 7, q = (idx >> 3) & 2047, bh = idx >> 14;
  const int b = bh >> 4, h = bh & 15;
  const size_t po = ((size_t)bh * 2048 + q) * 64 + d8 * 8;
  f32x4 a0 = *(const f32x4*)&O0[po];
  f32x4 a1 = *(const f32x4*)&O0[po + 4];
  f32x4 c0 = *(const f32x4*)&O1[po];
  f32x4 c1 = *(const f32x4*)&O1[po + 4];
  float l = lpart[(size_t)bh * 2048 + q] + lpart[(size_t)(32 + bh) * 2048 + q];
  float rl = 1.0f / l;
  union { __bf16 h8[8]; uint4 u; } pk;
#pragma unroll
  for (int r = 0; r < 4; r++) {
    pk.h8[r]     = (__bf16)((a0[r] + c0[r]) * rl);
    pk.h8[4 + r] = (__bf16)((a1[r] + c1[r]) * rl);
  }
  *(uint4*)&Obuf[((size_t)(b * 2048 + q)) * 1024 + h * 64 + d8 * 8] = pk.u;
}

extern "C" void kernel_launch(void* const* d_in, const int* in_sizes, int n_in,
                              void* d_out, int out_size, void* d_ws, size_t ws_size,
                              hipStream_t stream) {
  const void* x   = d_in[0];
  const void* rc  = d_in[1];
  const void* rs  = d_in[2];
  const void* Wq  = d_in[3];
  const void* bq  = d_in[4];
  const void* Wk  = d_in[5];
  const void* bk  = d_in[6];
  const void* Wv  = d_in[7];
  const void* bv  = d_in[8];
  const void* qnw = d_in[9];
  const void* qnb = d_in[10];
  const void* knw = d_in[11];
  const void* knb = d_in[12];
  const void* Wo  = d_in[13];
  const void* bo  = d_in[14];
  const unsigned short* xdet = (const unsigned short*)x;

  // temporal aliasing:
  //  [0, 16M)       O0 fp32 (attn -> combine)
  //  [16M, 32M)     O1 fp32; x_bf at 25.1M (prep -> gemm_qkv, fp32 path) dies before attn
  //  [33.5M, 41.9M) Qp (gemm_qkv -> attn), then Obuf (combine -> gemm1)
  char* ws = (char*)d_ws;
  float*  O0    = (float*)ws;
  float*  O1    = (float*)(ws + 16777216);
  __bf16* x_bf  = (__bf16*)(ws + 25165824);
  __bf16* Qp    = (__bf16*)(ws + 33554432);
  __bf16* Obuf  = (__bf16*)(ws + 33554432);
  __bf16* Kp    = (__bf16*)(ws + 41943040);
  __bf16* Vt    = (__bf16*)(ws + 50331648);
  __bf16* Wt    = (__bf16*)(ws + 58720256);   // [3072][1024] 6 MB
  __bf16* Wot   = (__bf16*)(ws + 65011712);   // [1024][1024] 2 MB
  float*  bias  = (float*)(ws + 67108864);    // [4096]
  float*  lprt  = (float*)(ws + 67125248);    // [2][32][2048] fp32

  prep<<<dim3(32, 32, 5), 256, 0, stream>>>(Wq, Wk, Wv, Wo, x, bq, bk, bv, bo,
                                            Wt, Wot, x_bf, bias);
  gemm_qkv<<<512, 256, 0, stream>>>(x_bf, (const __bf16*)x, Wt, bias, rc, rs,
                                    qnw, qnb, knw, knb, xdet, Qp, Kp, Vt);
  attn<<<1024, 256, 0, stream>>>(Qp, Kp, Vt, O0, O1, lprt);
  combine<<<2048, 256, 0, stream>>>(O0, O1, lprt, Obuf);
  gemm_bt<1, 64, 2><<<512, 256, 0, stream>>>(Obuf, Wot, bias + 3072,
                                             d_out, xdet, 4096, 1024, 1024);
}